// Round 3
// baseline (1489.873 us; speedup 1.0000x reference)
//
#include <hip/hip_runtime.h>

#define T_LEN 2048
#define HID   256
#define G4    1024
#define EMBD  128
#define VOCAB 128
#define OUTC  2
#define BSUB  2           // batch rows per chain
#define NWG   64
#define HSB   288         // habuf row stride bytes
#define LOG2E 1.44269504088896340736f

typedef int   i32x4 __attribute__((ext_vector_type(4)));
typedef float f32x4 __attribute__((ext_vector_type(4)));

// Device-global scratch rebuilt every launch (kernel-boundary coherence, no fences).
// Pbuf swizzled: [v][unit][g] -- each lane's 4 xg values are 16 contiguous bytes.
__device__ __align__(16) float Pbuf[VOCAB * G4];
__device__ __align__(16) signed char Wqb[G4 * HID];   // int8 W_hh, row-major [gatecol][k]
__device__ float Winv[G4];                            // m/(127^2) * per-gate exp2 scale

__global__ void build_P(const float* __restrict__ emb, const float* __restrict__ W_ih,
                        const float* __restrict__ b_ih, const float* __restrict__ b_hh) {
    const int v = blockIdx.x >> 2;
    const int c = ((blockIdx.x & 3) << 8) + threadIdx.x;   // gate-col 0..1023
    __shared__ float es[EMBD];
    if (threadIdx.x < EMBD) es[threadIdx.x] = emb[v * EMBD + threadIdx.x];
    __syncthreads();
    const float* wr = W_ih + c * EMBD;
    float acc = 0.f;
    #pragma unroll 8
    for (int e = 0; e < EMBD; ++e) acc += es[e] * wr[e];
    const float ks = ((c >> 8) == 2) ? (-2.f * LOG2E) : (-LOG2E);
    // c = g*256 + unit  ->  idx = v*1024 + unit*4 + g   (unit-major, 4 gates contig)
    const int g = c >> 8;
    const int u = c & 255;
    Pbuf[v * G4 + u * 4 + g] = (acc + b_ih[c] + b_hh[c]) * ks;
}

// per-row symmetric int8 quantization of W_hh (1024 rows x 256)
__global__ void quant_W(const float* __restrict__ W_hh) {
    const int row = blockIdx.x;
    const int k   = threadIdx.x;
    __shared__ float red[4];
    const float wv = W_hh[row * HID + k];
    float a = fabsf(wv);
    #pragma unroll
    for (int o = 32; o > 0; o >>= 1) a = fmaxf(a, __shfl_down(a, o, 64));
    if ((k & 63) == 0) red[k >> 6] = a;
    __syncthreads();
    const float m = fmaxf(fmaxf(fmaxf(red[0], red[1]), red[2]), fmaxf(red[3], 1e-30f));
    Wqb[row * HID + k] = (signed char)(int)rintf(wv * (127.f / m));
    const float ks = ((row >> 8) == 2) ? (-2.f * LOG2E) : (-LOG2E);
    if (k == 0) Winv[row] = m * (1.f / (127.f * 127.f)) * ks;
}

// 64 WGs x 1024 thr: one WG = one chain of 2 batch rows, 16 waves, wave owns
// 16 units x 4 gates (acc tile == gate). R13: same per-SIMD MFMA load (64/step,
// peak i8 rate) but Bf shrinks 128->64 regs -> 4 waves/SIMD instead of 2. The
// measured step = 1034 cyc MFMA phase + ~590 cyc NON-OVERLAPPED latency phase
// (tail chain + barrier + ds_read; R12 proved it is latency- not
// throughput-bound). 4-way wave interleave hides ~half of it. Tail loses the
// cndmask: gate preacts are a[g][0] directly (C-row = quad*4; quads 1,3 are
// M-redundancy duplicates, stores masked to quads 0,2).
__global__ __launch_bounds__(1024, 4) void lstm_chain(
        const int* __restrict__ x, const float* __restrict__ fc_W,
        const float* __restrict__ fc_b, float* __restrict__ out) {
    __shared__ __align__(16) signed char habuf[2][BSUB * HSB];
    __shared__ __align__(16) int xls[BSUB][T_LEN];   // pre-shifted byte offsets
    __shared__ float hfin[BSUB * HID];

    const int tid  = threadIdx.x;
    const int w    = tid >> 6;       // wave 0..15: owns units [16w, 16w+16)
    const int lane = tid & 63;
    const int l15  = lane & 15;
    const int quad = lane >> 4;
    const int bbase = blockIdx.x * BSUB;
    const int colq  = w * 16 + l15;           // this lane's unit
    const int bq    = quad >> 1;              // this lane's batch row
    const bool wact = !(quad & 1);            // quads 0,2 own cells; 1,3 duplicate

    // persistent int8 B fragments: 4 gates x 4 K-chunks x 4 regs = 64 regs
    i32x4 Bf[4][4];
    #pragma unroll
    for (int g = 0; g < 4; ++g) {
        const signed char* wr = Wqb + (size_t)(g * HID + colq) * HID;
        #pragma unroll
        for (int kt = 0; kt < 4; ++kt)
            Bf[g][kt] = *(const i32x4*)(wr + kt * 64 + quad * 16);
    }
    float winvv[4];                           // per-gate dequant for THIS lane's unit
    #pragma unroll
    for (int g = 0; g < 4; ++g) winvv[g] = Winv[g * HID + colq];

    // stage both x rows (contiguous in global), pre-shifted to Pbuf byte offsets
    {
        const i32x4* xsrc = (const i32x4*)(x + (size_t)bbase * T_LEN);
        i32x4 v0 = xsrc[tid];
        #pragma unroll
        for (int j = 0; j < 4; ++j) v0[j] <<= 12;   // *G4*4 bytes
        ((i32x4*)xls)[tid] = v0;
    }
    if (tid < BSUB * HSB / 4) ((int*)habuf[0])[tid] = 0;   // h_0 = 0

    float cst = 0.f;                          // single cell state per lane
    f32x4 xga, xgb;                           // double-buffered xg (4 gates)
    const i32x4 zero4 = {0, 0, 0, 0};
    const char* pbase = (const char*)(Pbuf + colq * 4);
    const signed char* habA = habuf[0] + (l15 >> 3) * HSB + quad * 16;
    const signed char* habB = habuf[1] + (l15 >> 3) * HSB + quad * 16;

#define GATHER(TT, XG)                                                        \
    {                                                                         \
        const int xo = xls[bq][(TT)];                                         \
        XG = *(const f32x4*)(pbase + xo);                                     \
    }

#define STEP(HAB, HN, XC, XN, PF, TT, TCUR)                                   \
    {                                                                         \
        const i32x4 af0 = *(const i32x4*)(HAB);                               \
        if (PF) GATHER((TT), XN);                                             \
        i32x4 a[4];                                                           \
        _Pragma("unroll")                                                     \
        for (int g = 0; g < 4; ++g)                                           \
            a[g] = __builtin_amdgcn_mfma_i32_16x16x64_i8(af0, Bf[g][0], zero4, 0, 0, 0); \
        _Pragma("unroll")                                                     \
        for (int kt = 1; kt < 4; ++kt) {                                      \
            const i32x4 afk = *(const i32x4*)((HAB) + kt * 64);               \
            _Pragma("unroll")                                                 \
            for (int g = 0; g < 4; ++g)                                       \
                a[g] = __builtin_amdgcn_mfma_i32_16x16x64_i8(afk, Bf[g][kt], a[g], 0, 0, 0); \
        }                                                                     \
        /* gate preacts directly: no tile cndmask (tile == gate) */           \
        const float pi = fmaf((float)a[0][0], winvv[0], XC[0]);               \
        const float pf = fmaf((float)a[1][0], winvv[1], XC[1]);               \
        const float pg = fmaf((float)a[2][0], winvv[2], XC[2]);               \
        const float po = fmaf((float)a[3][0], winvv[3], XC[3]);               \
        const float Ei = __builtin_amdgcn_exp2f(pi);                          \
        const float Ef = __builtin_amdgcn_exp2f(pf);                          \
        const float Eg = __builtin_amdgcn_exp2f(pg);                          \
        const float Eo = __builtin_amdgcn_exp2f(po);                          \
        const float Aig = (1.f + Ei) * (1.f + Eg);                            \
        const float R3  = __builtin_amdgcn_rcpf(Aig * (1.f + Ef));            \
        const float fs  = Aig * R3;                   /* sigma(f) */          \
        const float ig  = (1.f + Ef) * R3 * (1.f - Eg); /* sig(i)*tanh(g) */  \
        const float c   = fmaf(fs, cst, ig);                                  \
        cst = c;                                                              \
        const float Ec  = __builtin_amdgcn_exp2f(fminf(c * (-2.f * LOG2E), 60.f)); \
        const float R2  = __builtin_amdgcn_rcpf((1.f + Eo) * (1.f + Ec));     \
        const float hq  = fmaf(-127.f, Ec, 127.f) * R2;  /* 127*o*tanh(c) */  \
        if (wact) {                                                           \
            (HN)[bq * HSB + colq] = (signed char)(int)rintf(hq);              \
            if ((TCUR) == T_LEN - 1) hfin[bq * HID + colq] = hq * (1.f / 127.f); \
        }                                                                     \
        __syncthreads();                                                      \
    }

    __syncthreads();                          // xls + habuf[0] visible
    GATHER(0, xga);
    #pragma unroll 1
    for (int tt = 0; tt < T_LEN; tt += 2) {
        STEP(habA, habuf[1], xga, xgb, 1, tt + 1, tt);
        STEP(habB, habuf[0], xgb, xga, (tt < T_LEN - 2), tt + 2, tt + 1);
    }
#undef STEP
#undef GATHER

    // FC epilogue: logits[b,o] = hT[b,:] . fc_W[o,:] + fc_b[o]
    if (tid < BSUB * OUTC) {
        const int b = tid >> 1, o = tid & 1;
        float s = fc_b[o];
        #pragma unroll 8
        for (int j = 0; j < HID; ++j) s += hfin[b * HID + j] * fc_W[o * HID + j];
        out[(bbase + b) * OUTC + o] = s;
    }
}

extern "C" void kernel_launch(void* const* d_in, const int* in_sizes, int n_in,
                              void* d_out, int out_size, void* d_ws, size_t ws_size,
                              hipStream_t stream) {
    const int*   x    = (const int*)  d_in[0];
    const float* emb  = (const float*)d_in[1];
    const float* W_ih = (const float*)d_in[2];
    const float* W_hh = (const float*)d_in[3];
    const float* b_ih = (const float*)d_in[4];
    const float* b_hh = (const float*)d_in[5];
    const float* fc_W = (const float*)d_in[6];
    const float* fc_b = (const float*)d_in[7];
    float* out = (float*)d_out;
    (void)d_ws; (void)ws_size;

    build_P<<<dim3(VOCAB * 4), dim3(256), 0, stream>>>(emb, W_ih, b_ih, b_hh);
    quant_W<<<dim3(G4), dim3(HID), 0, stream>>>(W_hh);
    lstm_chain<<<dim3(NWG), dim3(1024), 0, stream>>>(x, fc_W, fc_b, out);
}